// Round 2
// baseline (916.563 us; speedup 1.0000x reference)
//
#include <hip/hip_runtime.h>
#include <hip/hip_bf16.h>

#define NN 100000   // nodes
#define NE 200000   // edges
#define NG 2500     // graphs
#define FN 16       // node feats
#define FE 8        // edge feats
#define H1C 32
#define H2C 16
#define KH 16       // edge-MLP hidden

__device__ __forceinline__ float bf2f(unsigned short u){
  union { unsigned int i; float f; } v; v.i = ((unsigned int)u) << 16; return v.f;
}

__device__ __forceinline__ int lower_bound_i(const int* __restrict__ a, int n, int v){
  int lo = 0, hi = n;
  while(lo < hi){ int mid = (lo + hi) >> 1; if(a[mid] < v) lo = mid + 1; else hi = mid; }
  return lo;
}

// flag = 1 if float inputs are bf16, 0 if fp32.
// Even-indexed ushorts of an fp32 array are mantissa bits -> random exponent when
// read as bf16 (~10% "sane"); genuine bf16 N(0,1) data is ~100% sane.
__global__ void detect_kernel(const void* __restrict__ x, int* __restrict__ flag){
  int tid = threadIdx.x;  // 256 threads
  const unsigned short* u = (const unsigned short*)x;
  float f = bf2f(u[2*tid]);
  float a = fabsf(f);
  int sane = (f == 0.0f) || (a > 1e-4f && a < 1e4f);  // NaN fails both -> not sane
  __shared__ int cnt;
  if(tid == 0) cnt = 0;
  __syncthreads();
  if(sane) atomicAdd(&cnt, 1);
  __syncthreads();
  if(tid == 0) *flag = (cnt >= 128) ? 1 : 0;
}

__global__ void cvt_any(const void* __restrict__ in, float* __restrict__ out, int n,
                        const int* __restrict__ flag){
  bool isbf = (*flag) != 0;
  int i = blockIdx.x * blockDim.x + threadIdx.x;
  int stride = gridDim.x * blockDim.x;
  if(isbf){
    const unsigned short* u = (const unsigned short*)in;
    for(; i < n; i += stride) out[i] = bf2f(u[i]);
  } else {
    const float* p = (const float*)in;
    for(; i < n; i += stride) out[i] = p[i];
  }
}

// ---- packed weight conversion: 20 tensors -> one contiguous fp32 region ----
#define NW 20
struct WArgs { const void* p[NW]; };

// element counts, dict order (w_e1a..b_l2)
#define W_TOTAL 19330
// fp32 ws offsets of each tensor (prefix sums of sizes below)
enum {
  OW_E1A=0,     OB_E1A=128,   OW_E1B=144,   OB_E1B=8336,  OW_R1=8848,  OB_R1=9360,
  OW_E2A=9392,  OB_E2A=9520,  OW_E2B=9536,  OB_E2B=17728, OW_R2=18240, OB_R2=18752,
  OW_G1=18768,  OB_G1=19024,  OW_G2=19040,  OB_G2=19056,
  OW_L1=19057,  OB_L1=19313,  OW_L2=19321,  OB_L2=19329
};

__global__ void cvt_weights_kernel(WArgs w, float* __restrict__ out, const int* __restrict__ flag){
  const int sz[NW] = {128,16,8192,512,512,32, 128,16,8192,512,512,16, 256,16,16,1, 256,8,8,1};
  bool isbf = (*flag) != 0;
  int i = blockIdx.x * blockDim.x + threadIdx.x;
  if(i >= W_TOTAL) return;
  int seg = 0, base = 0;
  while(i - base >= sz[seg]){ base += sz[seg]; seg++; }
  int off = i - base;
  out[i] = isbf ? bf2f(((const unsigned short*)w.p[seg])[off])
                : ((const float*)w.p[seg])[off];
}

// ---- gate MLP: gate = relu(x@w1+b1)@w2+b2 ----
__global__ void __launch_bounds__(256) gate_kernel(
    const float* __restrict__ xf, const float* __restrict__ w1, const float* __restrict__ b1,
    const float* __restrict__ w2, const float* __restrict__ b2, float* __restrict__ gate)
{
  __shared__ float s_w1[FN*FN], s_b1[FN], s_w2[FN], s_b2;
  if(threadIdx.x < FN*FN) s_w1[threadIdx.x] = w1[threadIdx.x];
  if(threadIdx.x < FN){ s_b1[threadIdx.x] = b1[threadIdx.x]; s_w2[threadIdx.x] = w2[threadIdx.x]; }
  if(threadIdx.x == 0) s_b2 = b2[0];
  __syncthreads();
  int n = blockIdx.x * 256 + threadIdx.x;
  if(n >= NN) return;
  float xv[FN];
  const float4* xp = (const float4*)(xf + (size_t)n * FN);
  #pragma unroll
  for(int q = 0; q < 4; q++){ float4 v = xp[q]; xv[q*4+0]=v.x; xv[q*4+1]=v.y; xv[q*4+2]=v.z; xv[q*4+3]=v.w; }
  float g = s_b2;
  #pragma unroll
  for(int j = 0; j < FN; j++){
    float hj = s_b1[j];
    #pragma unroll
    for(int i = 0; i < FN; i++) hj += xv[i] * s_w1[i*FN + j];
    hj = hj > 0.f ? hj : 0.f;
    g += hj * s_w2[j];
  }
  gate[n] = g;
}

// one wave per graph: segment softmax over gate, weighted sum of x
__global__ void attn_pool_kernel(const float* __restrict__ gate, const float* __restrict__ xf,
                                 const int* __restrict__ batch, float* __restrict__ x_att)
{
  int g = blockIdx.x;
  int lane = threadIdx.x;
  int start = lower_bound_i(batch, NN, g);
  int end   = lower_bound_i(batch, NN, g + 1);
  float m = -1e30f;
  for(int n = start + lane; n < end; n += 64) m = fmaxf(m, gate[n]);
  #pragma unroll
  for(int o = 32; o >= 1; o >>= 1) m = fmaxf(m, __shfl_xor(m, o));
  float s = 0.f;
  float acc[FN];
  #pragma unroll
  for(int f = 0; f < FN; f++) acc[f] = 0.f;
  for(int n = start + lane; n < end; n += 64){
    float a = __expf(gate[n] - m);
    s += a;
    const float4* xp = (const float4*)(xf + (size_t)n * FN);
    #pragma unroll
    for(int q = 0; q < 4; q++){
      float4 v = xp[q];
      acc[q*4+0] += a*v.x; acc[q*4+1] += a*v.y; acc[q*4+2] += a*v.z; acc[q*4+3] += a*v.w;
    }
  }
  #pragma unroll
  for(int o = 32; o >= 1; o >>= 1){
    s += __shfl_xor(s, o);
    #pragma unroll
    for(int f = 0; f < FN; f++) acc[f] += __shfl_xor(acc[f], o);
  }
  if(lane < FN){
    float v = (end > start && s > 0.f) ? acc[lane] / s : 0.f;
    x_att[g*FN + lane] = v;
  }
}

// fused NNConv message: h = relu(ea@wa+ba); msg[o] = sum_i x[i]*(bb[i,o] + sum_k h[k]*wb[k,i,o])
template<int IN_C, int OUT_C>
__global__ void __launch_bounds__(256) nnconv_edge_kernel(
    const float* __restrict__ nodef, const float* __restrict__ ef, const int* __restrict__ ei,
    const float* __restrict__ wa, const float* __restrict__ ba,
    const float* __restrict__ wb, const float* __restrict__ bb, float* __restrict__ agg)
{
  __shared__ float4 s_wb4[KH*IN_C*OUT_C/4];   // 32 KB
  __shared__ float4 s_bb4[IN_C*OUT_C/4];
  __shared__ float s_wa[FE*KH], s_ba[KH];
  float* s_wb = (float*)s_wb4;
  float* s_bb = (float*)s_bb4;
  for(int i = threadIdx.x; i < KH*IN_C*OUT_C; i += 256) s_wb[i] = wb[i];
  for(int i = threadIdx.x; i < IN_C*OUT_C; i += 256) s_bb[i] = bb[i];
  if(threadIdx.x < FE*KH) s_wa[threadIdx.x] = wa[threadIdx.x];
  if(threadIdx.x < KH) s_ba[threadIdx.x] = ba[threadIdx.x];
  __syncthreads();
  int e = blockIdx.x * 256 + threadIdx.x;
  if(e >= NE) return;

  float ev[FE];
  #pragma unroll
  for(int j = 0; j < FE; j++) ev[j] = ef[(size_t)e*FE + j];
  float h[KH];
  #pragma unroll
  for(int k = 0; k < KH; k++){
    float t = s_ba[k];
    #pragma unroll
    for(int j = 0; j < FE; j++) t += ev[j] * s_wa[j*KH + k];
    h[k] = t > 0.f ? t : 0.f;
  }
  int sn = ei[e];
  float xv[IN_C];
  const float4* xp = (const float4*)(nodef + (size_t)sn * IN_C);
  #pragma unroll
  for(int q = 0; q < IN_C/4; q++){ float4 v = xp[q]; xv[q*4+0]=v.x; xv[q*4+1]=v.y; xv[q*4+2]=v.z; xv[q*4+3]=v.w; }

  float4 msg[OUT_C/4];
  #pragma unroll
  for(int o = 0; o < OUT_C/4; o++) msg[o] = make_float4(0.f, 0.f, 0.f, 0.f);

  for(int i = 0; i < IN_C; i++){
    float xi = xv[i];
    #pragma unroll
    for(int o = 0; o < OUT_C/4; o++){
      float4 t = s_bb4[i*(OUT_C/4) + o];
      #pragma unroll
      for(int k = 0; k < KH; k++){
        float4 w = s_wb4[k*(IN_C*OUT_C/4) + i*(OUT_C/4) + o];
        t.x += h[k]*w.x; t.y += h[k]*w.y; t.z += h[k]*w.z; t.w += h[k]*w.w;
      }
      msg[o].x += xi*t.x; msg[o].y += xi*t.y; msg[o].z += xi*t.z; msg[o].w += xi*t.w;
    }
  }
  int tn = ei[NE + e];
  float* ag = agg + (size_t)tn * OUT_C;
  #pragma unroll
  for(int o = 0; o < OUT_C/4; o++){
    atomicAdd(ag + o*4 + 0, msg[o].x);
    atomicAdd(ag + o*4 + 1, msg[o].y);
    atomicAdd(ag + o*4 + 2, msg[o].z);
    atomicAdd(ag + o*4 + 3, msg[o].w);
  }
}

// h1 = relu(x @ wr + br + agg)
__global__ void __launch_bounds__(256) node_update1_kernel(
    const float* __restrict__ xin, const float* __restrict__ agg,
    const float* __restrict__ wr, const float* __restrict__ br, float* __restrict__ out)
{
  __shared__ float s_w[FN*H1C], s_b[H1C];
  for(int i = threadIdx.x; i < FN*H1C; i += 256) s_w[i] = wr[i];
  if(threadIdx.x < H1C) s_b[threadIdx.x] = br[threadIdx.x];
  __syncthreads();
  int n = blockIdx.x * 256 + threadIdx.x;
  if(n >= NN) return;
  float xv[FN];
  const float4* xp = (const float4*)(xin + (size_t)n * FN);
  #pragma unroll
  for(int q = 0; q < FN/4; q++){ float4 v = xp[q]; xv[q*4+0]=v.x; xv[q*4+1]=v.y; xv[q*4+2]=v.z; xv[q*4+3]=v.w; }
  #pragma unroll
  for(int o = 0; o < H1C; o++){
    float t = s_b[o] + agg[(size_t)n*H1C + o];
    #pragma unroll
    for(int i = 0; i < FN; i++) t += xv[i] * s_w[i*H1C + o];
    out[(size_t)n*H1C + o] = t > 0.f ? t : 0.f;
  }
}

// h2 = relu(h1 @ wr + br + agg); atomically accumulate per-graph sum (mean pool numerator)
__global__ void __launch_bounds__(256) node_update2_kernel(
    const float* __restrict__ xin, const float* __restrict__ agg,
    const float* __restrict__ wr, const float* __restrict__ br,
    const int* __restrict__ batch, float* __restrict__ mean_acc)
{
  __shared__ float s_w[H1C*H2C], s_b[H2C];
  for(int i = threadIdx.x; i < H1C*H2C; i += 256) s_w[i] = wr[i];
  if(threadIdx.x < H2C) s_b[threadIdx.x] = br[threadIdx.x];
  __syncthreads();
  int n = blockIdx.x * 256 + threadIdx.x;
  if(n >= NN) return;
  float xv[H1C];
  const float4* xp = (const float4*)(xin + (size_t)n * H1C);
  #pragma unroll
  for(int q = 0; q < H1C/4; q++){ float4 v = xp[q]; xv[q*4+0]=v.x; xv[q*4+1]=v.y; xv[q*4+2]=v.z; xv[q*4+3]=v.w; }
  int g = batch[n];
  float* mp = mean_acc + (size_t)g * H2C;
  #pragma unroll
  for(int o = 0; o < H2C; o++){
    float t = s_b[o] + agg[(size_t)n*H2C + o];
    #pragma unroll
    for(int i = 0; i < H1C; i++) t += xv[i] * s_w[i*H2C + o];
    t = t > 0.f ? t : 0.f;
    atomicAdd(mp + o, t);
  }
}

// per-graph: mean = acc/cnt, concat x_att, 2-layer head, dtype-flagged output write
__global__ void head_kernel(const float* __restrict__ mean_acc, const float* __restrict__ x_att,
    const int* __restrict__ batch,
    const float* __restrict__ wl1, const float* __restrict__ bl1,
    const float* __restrict__ wl2, const float* __restrict__ bl2,
    void* __restrict__ out, const int* __restrict__ flag)
{
  int g = blockIdx.x * blockDim.x + threadIdx.x;
  if(g >= NG) return;
  int start = lower_bound_i(batch, NN, g);
  int end   = lower_bound_i(batch, NN, g + 1);
  float inv = 1.f / fmaxf((float)(end - start), 1.f);
  float z[H2C + FN];
  #pragma unroll
  for(int f = 0; f < H2C; f++) z[f] = mean_acc[(size_t)g*H2C + f] * inv;
  #pragma unroll
  for(int f = 0; f < FN; f++) z[H2C + f] = x_att[(size_t)g*FN + f];
  float t1[8];
  #pragma unroll
  for(int j = 0; j < 8; j++){
    float t = bl1[j];
    #pragma unroll
    for(int c = 0; c < H2C + FN; c++) t += z[c] * wl1[c*8 + j];
    t1[j] = t;
  }
  float o = bl2[0];
  #pragma unroll
  for(int j = 0; j < 8; j++) o += t1[j] * wl2[j];
  if((*flag) != 0) ((__hip_bfloat16*)out)[g] = __float2bfloat16(o);
  else             ((float*)out)[g] = o;
}

extern "C" void kernel_launch(void* const* d_in, const int* in_sizes, int n_in,
                              void* d_out, int out_size, void* d_ws, size_t ws_size,
                              hipStream_t stream)
{
  const int* ei    = (const int*)d_in[22];
  const int* batch = (const int*)d_in[23];

  float* ws = (float*)d_ws;
  float* xf    = ws;                       // NN*FN   = 1,600,000
  float* ef    = xf    + (size_t)NN*FN;    // NE*FE   = 1,600,000
  float* gate  = ef    + (size_t)NE*FE;    // NN      =   100,000
  float* x_att = gate  + NN;               // NG*FN   =    40,000
  float* wts   = x_att + (size_t)NG*FN;    // 19,332 (padded)
  float* agg1  = wts   + 19332;            // NN*H1C  = 3,200,000 (agg2 aliases first NN*H2C)
  float* h1b   = agg1  + (size_t)NN*H1C;   // NN*H1C  = 3,200,000
  float* mean_acc = h1b + (size_t)NN*H1C;  // NG*H2C  =    40,000
  int*   flag  = (int*)(mean_acc + (size_t)NG*H2C);
  float* agg2  = agg1;                     // reused after node_update1 consumes agg1

  WArgs wa;
  for(int i = 0; i < NW; i++) wa.p[i] = d_in[2 + i];

  detect_kernel<<<1, 256, 0, stream>>>(d_in[0], flag);
  hipMemsetAsync(agg1, 0, (size_t)NN*H1C*sizeof(float), stream);
  cvt_any<<<512, 256, 0, stream>>>(d_in[0], xf, NN*FN, flag);
  cvt_any<<<512, 256, 0, stream>>>(d_in[1], ef, NE*FE, flag);
  cvt_weights_kernel<<<(W_TOTAL + 255)/256, 256, 0, stream>>>(wa, wts, flag);

  gate_kernel<<<(NN + 255)/256, 256, 0, stream>>>(xf, wts+OW_G1, wts+OB_G1, wts+OW_G2, wts+OB_G2, gate);
  attn_pool_kernel<<<NG, 64, 0, stream>>>(gate, xf, batch, x_att);

  nnconv_edge_kernel<FN, H1C><<<(NE + 255)/256, 256, 0, stream>>>(
      xf, ef, ei, wts+OW_E1A, wts+OB_E1A, wts+OW_E1B, wts+OB_E1B, agg1);
  node_update1_kernel<<<(NN + 255)/256, 256, 0, stream>>>(xf, agg1, wts+OW_R1, wts+OB_R1, h1b);

  hipMemsetAsync(agg2, 0, (size_t)NN*H2C*sizeof(float), stream);   // after node_update1 (stream-ordered)
  hipMemsetAsync(mean_acc, 0, (size_t)NG*H2C*sizeof(float), stream);

  nnconv_edge_kernel<H1C, H2C><<<(NE + 255)/256, 256, 0, stream>>>(
      h1b, ef, ei, wts+OW_E2A, wts+OB_E2A, wts+OW_E2B, wts+OB_E2B, agg2);
  node_update2_kernel<<<(NN + 255)/256, 256, 0, stream>>>(
      h1b, agg2, wts+OW_R2, wts+OB_R2, batch, mean_acc);

  head_kernel<<<(NG + 255)/256, 256, 0, stream>>>(
      mean_acc, x_att, batch, wts+OW_L1, wts+OB_L1, wts+OW_L2, wts+OB_L2, d_out, flag);
}

// Round 3
// 452.800 us; speedup vs baseline: 2.0242x; 2.0242x over previous
//
#include <hip/hip_runtime.h>
#include <hip/hip_bf16.h>

#define NN 100000   // nodes
#define NE 200000   // edges
#define NG 2500     // graphs
#define FN 16       // node feats
#define FE 8        // edge feats
#define H1C 32
#define H2C 16
#define KH 16       // edge-MLP hidden

typedef __attribute__((ext_vector_type(8))) short short8;
typedef __attribute__((ext_vector_type(4))) float f32x4;

__device__ __forceinline__ float bf2f(unsigned int u){
  union { unsigned int i; float f; } v; v.i = (u & 0xffffu) << 16; return v.f;
}
__device__ __forceinline__ unsigned short f2bf(float f){
  union { float f; unsigned int i; } u; u.f = f;
  unsigned int r = u.i + 0x7fffu + ((u.i >> 16) & 1u);   // RNE, finite data
  return (unsigned short)(r >> 16);
}
__device__ __forceinline__ int lower_bound_i(const int* __restrict__ a, int n, int v){
  int lo = 0, hi = n;
  while(lo < hi){ int mid = (lo + hi) >> 1; if(a[mid] < v) lo = mid + 1; else hi = mid; }
  return lo;
}

// flag=1 if float inputs are bf16, 0 if fp32 (even ushorts of fp32 = mantissa bits -> insane exponents)
__global__ void detect_kernel(const void* __restrict__ x, int* __restrict__ flag){
  int tid = threadIdx.x;
  const unsigned short* u = (const unsigned short*)x;
  float f = bf2f(u[2*tid]);
  float a = fabsf(f);
  int sane = (f == 0.0f) || (a > 1e-4f && a < 1e4f);
  __shared__ int cnt;
  if(tid == 0) cnt = 0;
  __syncthreads();
  if(sane) atomicAdd(&cnt, 1);
  __syncthreads();
  if(tid == 0) *flag = (cnt >= 128) ? 1 : 0;
}

__global__ void cvt_any(const void* __restrict__ in, float* __restrict__ out, int n,
                        const int* __restrict__ flag){
  bool isbf = (*flag) != 0;
  int i = blockIdx.x * blockDim.x + threadIdx.x;
  int stride = gridDim.x * blockDim.x;
  if(isbf){
    const unsigned short* u = (const unsigned short*)in;
    for(; i < n; i += stride) out[i] = bf2f(u[i]);
  } else {
    const float* p = (const float*)in;
    for(; i < n; i += stride) out[i] = p[i];
  }
}

#define NW 20
struct WArgs { const void* p[NW]; };
#define W_TOTAL 19330
enum {
  OW_E1A=0,     OB_E1A=128,   OW_E1B=144,   OB_E1B=8336,  OW_R1=8848,  OB_R1=9360,
  OW_E2A=9392,  OB_E2A=9520,  OW_E2B=9536,  OB_E2B=17728, OW_R2=18240, OB_R2=18752,
  OW_G1=18768,  OB_G1=19024,  OW_G2=19040,  OB_G2=19056,
  OW_L1=19057,  OB_L1=19313,  OW_L2=19321,  OB_L2=19329
};

__global__ void cvt_weights_kernel(WArgs w, float* __restrict__ out, const int* __restrict__ flag){
  const int sz[NW] = {128,16,8192,512,512,32, 128,16,8192,512,512,16, 256,16,16,1, 256,8,8,1};
  bool isbf = (*flag) != 0;
  int i = blockIdx.x * blockDim.x + threadIdx.x;
  if(i >= W_TOTAL) return;
  int seg = 0, base = 0;
  while(i - base >= sz[seg]){ base += sz[seg]; seg++; }
  int off = i - base;
  out[i] = isbf ? bf2f(((const unsigned short*)w.p[seg])[off])
                : ((const float*)w.p[seg])[off];
}

// ---- gate MLP ----
__global__ void __launch_bounds__(256) gate_kernel(
    const float* __restrict__ xf, const float* __restrict__ w1, const float* __restrict__ b1,
    const float* __restrict__ w2, const float* __restrict__ b2, float* __restrict__ gate)
{
  __shared__ float s_w1[FN*FN], s_b1[FN], s_w2[FN], s_b2;
  if(threadIdx.x < FN*FN) s_w1[threadIdx.x] = w1[threadIdx.x];
  if(threadIdx.x < FN){ s_b1[threadIdx.x] = b1[threadIdx.x]; s_w2[threadIdx.x] = w2[threadIdx.x]; }
  if(threadIdx.x == 0) s_b2 = b2[0];
  __syncthreads();
  int n = blockIdx.x * 256 + threadIdx.x;
  if(n >= NN) return;
  float xv[FN];
  const float4* xp = (const float4*)(xf + (size_t)n * FN);
  #pragma unroll
  for(int q = 0; q < 4; q++){ float4 v = xp[q]; xv[q*4+0]=v.x; xv[q*4+1]=v.y; xv[q*4+2]=v.z; xv[q*4+3]=v.w; }
  float g = s_b2;
  #pragma unroll
  for(int j = 0; j < FN; j++){
    float hj = s_b1[j];
    #pragma unroll
    for(int i = 0; i < FN; i++) hj += xv[i] * s_w1[i*FN + j];
    hj = hj > 0.f ? hj : 0.f;
    g += hj * s_w2[j];
  }
  gate[n] = g;
}

// one wave per graph: segment softmax + weighted x sum
__global__ void attn_pool_kernel(const float* __restrict__ gate, const float* __restrict__ xf,
                                 const int* __restrict__ batch, float* __restrict__ x_att)
{
  int g = blockIdx.x;
  int lane = threadIdx.x;
  int start = lower_bound_i(batch, NN, g);
  int end   = lower_bound_i(batch, NN, g + 1);
  float m = -1e30f;
  for(int n = start + lane; n < end; n += 64) m = fmaxf(m, gate[n]);
  #pragma unroll
  for(int o = 32; o >= 1; o >>= 1) m = fmaxf(m, __shfl_xor(m, o));
  float s = 0.f;
  float acc[FN];
  #pragma unroll
  for(int f = 0; f < FN; f++) acc[f] = 0.f;
  for(int n = start + lane; n < end; n += 64){
    float a = __expf(gate[n] - m);
    s += a;
    const float4* xp = (const float4*)(xf + (size_t)n * FN);
    #pragma unroll
    for(int q = 0; q < 4; q++){
      float4 v = xp[q];
      acc[q*4+0] += a*v.x; acc[q*4+1] += a*v.y; acc[q*4+2] += a*v.z; acc[q*4+3] += a*v.w;
    }
  }
  #pragma unroll
  for(int o = 32; o >= 1; o >>= 1){
    s += __shfl_xor(s, o);
    #pragma unroll
    for(int f = 0; f < FN; f++) acc[f] += __shfl_xor(acc[f], o);
  }
  if(lane < FN){
    float v = (end > start && s > 0.f) ? acc[lane] / s : 0.f;
    x_att[g*FN + lane] = v;
  }
}

// ---- CSR build (counting sort by tgt) ----
__global__ void histo_kernel(const int* __restrict__ ei, int* __restrict__ deg){
  int e = blockIdx.x*256 + threadIdx.x;
  if(e < NE) atomicAdd(&deg[ei[NE + e]], 1);
}
__global__ void scan1_kernel(const int* __restrict__ deg, int* __restrict__ bsum){
  __shared__ int s[256];
  int i = blockIdx.x*256 + threadIdx.x;
  s[threadIdx.x] = (i < NN) ? deg[i] : 0;
  __syncthreads();
  for(int off=128; off>0; off>>=1){
    if(threadIdx.x < off) s[threadIdx.x] += s[threadIdx.x+off];
    __syncthreads();
  }
  if(threadIdx.x==0) bsum[blockIdx.x] = s[0];
}
__global__ void scan2_kernel(int* __restrict__ bsum, int nb){
  __shared__ int s[512];
  int t = threadIdx.x;
  s[t] = (t < nb) ? bsum[t] : 0;
  __syncthreads();
  for(int off=1; off<512; off<<=1){
    int tv = (t>=off) ? s[t-off] : 0;
    __syncthreads();
    s[t] += tv;
    __syncthreads();
  }
  if(t < nb) bsum[t] = s[t];   // inclusive
}
__global__ void scan3_kernel(const int* __restrict__ deg, const int* __restrict__ bsum,
                             int* __restrict__ rowptr, int* __restrict__ cursor){
  __shared__ int s[256];
  int t = threadIdx.x;
  int i = blockIdx.x*256 + t;
  int v = (i < NN) ? deg[i] : 0;
  s[t] = v;
  __syncthreads();
  for(int off=1; off<256; off<<=1){
    int tv = (t>=off) ? s[t-off] : 0;
    __syncthreads();
    s[t] += tv;
    __syncthreads();
  }
  int bpre = (blockIdx.x==0) ? 0 : bsum[blockIdx.x-1];
  int excl = bpre + s[t] - v;
  if(i < NN){
    rowptr[i] = excl; cursor[i] = excl;
    if(i == NN-1) rowptr[NN] = excl + v;
  }
}
__global__ void fill_kernel(const int* __restrict__ ei, int* __restrict__ cursor, int* __restrict__ csr){
  int e = blockIdx.x*256 + threadIdx.x;
  if(e < NE){ int pos = atomicAdd(&cursor[ei[NE+e]], 1); csr[pos] = e; }
}

// ---- fused NNConv message GEMM via MFMA ----
// msg = P @ W, P[e,:] = [h(e) (x) x_src(e) | x_src(e) | 0pad] bf16, W = [wb; bb; 0] bf16
template<int IN, int OUT, int EPB>
__global__ void __launch_bounds__(EPB*4) conv_mfma_kernel(
    const float* __restrict__ nodef, const float* __restrict__ ef, const int* __restrict__ ei,
    const float* __restrict__ wa, const float* __restrict__ ba,
    const float* __restrict__ wb, const float* __restrict__ bb,
    unsigned short* __restrict__ msg)
{
  constexpr int KIN  = KH*IN;
  constexpr int KTOT = KIN + IN;
  constexpr int KMF  = ((KTOT + 31)/32)*32;   // conv1: 288, conv2: 544
  constexpr int KP   = KMF + 8;               // +8 bf16 pad breaks LDS stride conflicts
  constexpr int NT   = OUT/16;
  constexpr int NTHR = EPB*4;
  __shared__ __align__(16) unsigned short sP[EPB*KP];
  __shared__ __align__(16) unsigned short sW[OUT*KP];
  __shared__ float s_wa[FE*KH];
  __shared__ float s_ba[KH];
  int tid = threadIdx.x;

  for(int i = tid; i < FE*KH; i += NTHR) s_wa[i] = wa[i];
  if(tid < KH) s_ba[tid] = ba[tid];
  // W^T in LDS: sW[n*KP + k] = W[k][n]
  unsigned int* sWu = (unsigned int*)sW;
  for(int j = tid; j < OUT*(KP/2); j += NTHR){
    int n = j / (KP/2); int k = (j % (KP/2)) * 2;
    unsigned short v0 = 0, v1 = 0;
    if(k < KIN)        v0 = f2bf(wb[(size_t)k*OUT + n]);
    else if(k < KTOT)  v0 = f2bf(bb[(size_t)(k-KIN)*OUT + n]);
    if(k+1 < KIN)      v1 = f2bf(wb[(size_t)(k+1)*OUT + n]);
    else if(k+1 < KTOT)v1 = f2bf(bb[(size_t)(k+1-KIN)*OUT + n]);
    sWu[j] = (unsigned int)v0 | ((unsigned int)v1 << 16);
  }

  // per-edge loads (4 threads per edge)
  int e_loc = tid >> 2, p = tid & 3;
  int e = blockIdx.x*EPB + e_loc;          // grids are exact multiples
  float ev[FE];
  {
    const float4* ep = (const float4*)(ef + (size_t)e*FE);
    float4 a = ep[0], b = ep[1];
    ev[0]=a.x; ev[1]=a.y; ev[2]=a.z; ev[3]=a.w; ev[4]=b.x; ev[5]=b.y; ev[6]=b.z; ev[7]=b.w;
  }
  int sn = ei[e];
  float xv[IN];
  {
    const float4* xp = (const float4*)(nodef + (size_t)sn*IN);
    #pragma unroll
    for(int q = 0; q < IN/4; q++){ float4 v = xp[q]; xv[q*4+0]=v.x; xv[q*4+1]=v.y; xv[q*4+2]=v.z; xv[q*4+3]=v.w; }
  }
  __syncthreads();   // s_wa/s_ba/sW ready

  float h[4];
  #pragma unroll
  for(int kk = 0; kk < 4; kk++){
    int hid = p*4 + kk;
    float t = s_ba[hid];
    #pragma unroll
    for(int j = 0; j < FE; j++) t += ev[j] * s_wa[j*KH + hid];
    h[kk] = t > 0.f ? t : 0.f;
  }
  unsigned int* sPu = (unsigned int*)sP;
  int rowb = e_loc*KP;   // KP even
  #pragma unroll
  for(int kk = 0; kk < 4; kk++){
    int hid = p*4 + kk;
    float hv = h[kk];
    int cb = (rowb + hid*IN) >> 1;
    #pragma unroll
    for(int i2 = 0; i2 < IN/2; i2++){
      unsigned int u = (unsigned int)f2bf(hv*xv[2*i2]) | ((unsigned int)f2bf(hv*xv[2*i2+1]) << 16);
      sPu[cb + i2] = u;
    }
  }
  if(p == 0){   // x columns (bb term)
    int cb = (rowb + KIN) >> 1;
    #pragma unroll
    for(int i2 = 0; i2 < IN/2; i2++){
      unsigned int u = (unsigned int)f2bf(xv[2*i2]) | ((unsigned int)f2bf(xv[2*i2+1]) << 16);
      sPu[cb + i2] = u;
    }
  }
  if(p == 1 && KMF > KTOT){   // zero the K padding (undefined LDS could be NaN)
    int cb = (rowb + KTOT) >> 1;
    #pragma unroll
    for(int c = 0; c < (KMF-KTOT)/2; c++) sPu[cb + c] = 0;
  }
  __syncthreads();

  // MFMA: wave w handles 16 edges x OUT
  int lane = tid & 63;
  int w = tid >> 6;
  int m0 = w*16;
  int nrow = lane & 15, quad = lane >> 4;
  f32x4 acc[NT];
  #pragma unroll
  for(int nt = 0; nt < NT; nt++) acc[nt] = (f32x4){0.f,0.f,0.f,0.f};
  #pragma unroll
  for(int ks = 0; ks < KMF/32; ks++){
    short8 a = *(const short8*)&sP[(m0 + nrow)*KP + ks*32 + quad*8];
    #pragma unroll
    for(int nt = 0; nt < NT; nt++){
      short8 b = *(const short8*)&sW[(nt*16 + nrow)*KP + ks*32 + quad*8];
      acc[nt] = __builtin_amdgcn_mfma_f32_16x16x32_bf16(a, b, acc[nt], 0, 0, 0);
    }
  }
  int ebase = blockIdx.x*EPB + m0;
  #pragma unroll
  for(int nt = 0; nt < NT; nt++){
    #pragma unroll
    for(int r = 0; r < 4; r++){
      int m = quad*4 + r;   // C layout: row=(lane>>4)*4+reg, col=lane&15
      msg[(size_t)(ebase + m)*OUT + nt*16 + nrow] = f2bf(acc[nt][r]);
    }
  }
}

// h1 = relu(x@wr1 + br1 + gather(msg1)); 8 threads/node
__global__ void __launch_bounds__(256) gather1_kernel(
    const float* __restrict__ xf, const unsigned short* __restrict__ msg,
    const int* __restrict__ rowptr, const int* __restrict__ csr,
    const float* __restrict__ wr, const float* __restrict__ br, float* __restrict__ h1)
{
  __shared__ float s_w[FN*H1C], s_b[H1C];
  for(int i = threadIdx.x; i < FN*H1C; i += 256) s_w[i] = wr[i];
  if(threadIdx.x < H1C) s_b[threadIdx.x] = br[threadIdx.x];
  __syncthreads();
  int g = blockIdx.x*256 + threadIdx.x;
  int n = g >> 3, q = g & 7;
  if(n >= NN) return;
  float a0 = s_b[q*4+0], a1 = s_b[q*4+1], a2 = s_b[q*4+2], a3 = s_b[q*4+3];
  int jb = rowptr[n], je = rowptr[n+1];
  for(int j = jb; j < je; j++){
    int eid = csr[j];
    const unsigned int* mp = (const unsigned int*)(msg + (size_t)eid*H1C + q*4);
    unsigned int u0 = mp[0], u1 = mp[1];
    a0 += bf2f(u0); a1 += bf2f(u0 >> 16); a2 += bf2f(u1); a3 += bf2f(u1 >> 16);
  }
  const float* xr = xf + (size_t)n*FN;
  #pragma unroll
  for(int i = 0; i < FN; i++){
    float xi = xr[i];
    a0 += xi*s_w[i*H1C + q*4+0]; a1 += xi*s_w[i*H1C + q*4+1];
    a2 += xi*s_w[i*H1C + q*4+2]; a3 += xi*s_w[i*H1C + q*4+3];
  }
  float4 r; r.x = a0>0.f?a0:0.f; r.y = a1>0.f?a1:0.f; r.z = a2>0.f?a2:0.f; r.w = a3>0.f?a3:0.f;
  *(float4*)(h1 + (size_t)n*H1C + q*4) = r;
}

// h2 = relu(h1@wr2 + br2 + gather(msg2)); 4 threads/node
__global__ void __launch_bounds__(256) gather2_kernel(
    const float* __restrict__ h1, const unsigned short* __restrict__ msg,
    const int* __restrict__ rowptr, const int* __restrict__ csr,
    const float* __restrict__ wr, const float* __restrict__ br, float* __restrict__ h2)
{
  __shared__ float s_w[H1C*H2C], s_b[H2C];
  for(int i = threadIdx.x; i < H1C*H2C; i += 256) s_w[i] = wr[i];
  if(threadIdx.x < H2C) s_b[threadIdx.x] = br[threadIdx.x];
  __syncthreads();
  int g = blockIdx.x*256 + threadIdx.x;
  int n = g >> 2, q = g & 3;
  if(n >= NN) return;
  float a0 = s_b[q*4+0], a1 = s_b[q*4+1], a2 = s_b[q*4+2], a3 = s_b[q*4+3];
  int jb = rowptr[n], je = rowptr[n+1];
  for(int j = jb; j < je; j++){
    int eid = csr[j];
    const unsigned int* mp = (const unsigned int*)(msg + (size_t)eid*H2C + q*4);
    unsigned int u0 = mp[0], u1 = mp[1];
    a0 += bf2f(u0); a1 += bf2f(u0 >> 16); a2 += bf2f(u1); a3 += bf2f(u1 >> 16);
  }
  const float* hr = h1 + (size_t)n*H1C;
  #pragma unroll
  for(int i = 0; i < H1C; i++){
    float xi = hr[i];
    a0 += xi*s_w[i*H2C + q*4+0]; a1 += xi*s_w[i*H2C + q*4+1];
    a2 += xi*s_w[i*H2C + q*4+2]; a3 += xi*s_w[i*H2C + q*4+3];
  }
  float4 r; r.x = a0>0.f?a0:0.f; r.y = a1>0.f?a1:0.f; r.z = a2>0.f?a2:0.f; r.w = a3>0.f?a3:0.f;
  *(float4*)(h2 + (size_t)n*H2C + q*4) = r;
}

// one wave per graph: mean-pool h2 + concat x_att + 2-layer head
__global__ void head_kernel(const float* __restrict__ h2, const float* __restrict__ x_att,
    const int* __restrict__ batch,
    const float* __restrict__ wl1, const float* __restrict__ bl1,
    const float* __restrict__ wl2, const float* __restrict__ bl2,
    void* __restrict__ out, const int* __restrict__ flag)
{
  int g = blockIdx.x;
  int lane = threadIdx.x;
  int start = lower_bound_i(batch, NN, g);
  int end   = lower_bound_i(batch, NN, g + 1);
  float acc[H2C];
  #pragma unroll
  for(int f = 0; f < H2C; f++) acc[f] = 0.f;
  for(int n = start + lane; n < end; n += 64){
    const float4* hp = (const float4*)(h2 + (size_t)n*H2C);
    #pragma unroll
    for(int q = 0; q < 4; q++){
      float4 v = hp[q];
      acc[q*4+0] += v.x; acc[q*4+1] += v.y; acc[q*4+2] += v.z; acc[q*4+3] += v.w;
    }
  }
  #pragma unroll
  for(int o = 32; o >= 1; o >>= 1){
    #pragma unroll
    for(int f = 0; f < H2C; f++) acc[f] += __shfl_xor(acc[f], o);
  }
  if(lane == 0){
    float inv = 1.f / fmaxf((float)(end - start), 1.f);
    float z[H2C + FN];
    #pragma unroll
    for(int f = 0; f < H2C; f++) z[f] = acc[f] * inv;
    #pragma unroll
    for(int f = 0; f < FN; f++) z[H2C + f] = x_att[(size_t)g*FN + f];
    float t1[8];
    #pragma unroll
    for(int j = 0; j < 8; j++){
      float t = bl1[j];
      #pragma unroll
      for(int c = 0; c < H2C + FN; c++) t += z[c] * wl1[c*8 + j];
      t1[j] = t;
    }
    float o = bl2[0];
    #pragma unroll
    for(int j = 0; j < 8; j++) o += t1[j] * wl2[j];
    if((*flag) != 0) ((__hip_bfloat16*)out)[g] = __float2bfloat16(o);
    else             ((float*)out)[g] = o;
  }
}

extern "C" void kernel_launch(void* const* d_in, const int* in_sizes, int n_in,
                              void* d_out, int out_size, void* d_ws, size_t ws_size,
                              hipStream_t stream)
{
  const int* ei    = (const int*)d_in[22];
  const int* batch = (const int*)d_in[23];

  float* ws = (float*)d_ws;
  float* xf     = ws;                          // 1,600,000 f
  float* ef     = xf + 1600000;                // 1,600,000 f
  float* gate   = ef + 1600000;                //   100,000 f
  float* x_att  = gate + 100000;               //    40,000 f
  float* wts    = x_att + 40000;               //    19,360 f
  int*   rowptr = (int*)(wts + 19360);         //   100,016 i
  int*   cursor = rowptr + 100016;             //   100,000 i
  int*   deg    = cursor + 100000;             //   100,000 i
  int*   bsum   = deg + 100000;                //       512 i
  int*   csr    = bsum + 512;                  //   200,000 i
  int*   flagp  = csr + 200000;                //        16 i
  float* h1     = (float*)(flagp + 16);        // 3,200,000 f
  unsigned short* msg1 = (unsigned short*)(h1 + 3200000);  // 6,400,000 us (3.2M f)
  float* h2     = (float*)(msg1 + 6400000);    // 1,600,000 f
  unsigned short* msg2 = msg1;                 // reuse after gather1  -> total ~47.4 MB

  WArgs wa;
  for(int i = 0; i < NW; i++) wa.p[i] = d_in[2 + i];

  detect_kernel<<<1, 256, 0, stream>>>(d_in[0], flagp);
  cvt_any<<<512, 256, 0, stream>>>(d_in[0], xf, NN*FN, flagp);
  cvt_any<<<512, 256, 0, stream>>>(d_in[1], ef, NE*FE, flagp);
  cvt_weights_kernel<<<(W_TOTAL + 255)/256, 256, 0, stream>>>(wa, wts, flagp);
  hipMemsetAsync(deg, 0, NN*sizeof(int), stream);

  gate_kernel<<<(NN + 255)/256, 256, 0, stream>>>(xf, wts+OW_G1, wts+OB_G1, wts+OW_G2, wts+OB_G2, gate);
  attn_pool_kernel<<<NG, 64, 0, stream>>>(gate, xf, batch, x_att);

  const int NB1 = (NN + 255)/256;  // 391
  histo_kernel<<<(NE + 255)/256, 256, 0, stream>>>(ei, deg);
  scan1_kernel<<<NB1, 256, 0, stream>>>(deg, bsum);
  scan2_kernel<<<1, 512, 0, stream>>>(bsum, NB1);
  scan3_kernel<<<NB1, 256, 0, stream>>>(deg, bsum, rowptr, cursor);
  fill_kernel<<<(NE + 255)/256, 256, 0, stream>>>(ei, cursor, csr);

  conv_mfma_kernel<FN, H1C, 64><<<NE/64, 256, 0, stream>>>(
      xf, ef, ei, wts+OW_E1A, wts+OB_E1A, wts+OW_E1B, wts+OB_E1B, msg1);
  gather1_kernel<<<(NN*8 + 255)/256, 256, 0, stream>>>(xf, msg1, rowptr, csr, wts+OW_R1, wts+OB_R1, h1);

  conv_mfma_kernel<H1C, H2C, 32><<<NE/32, 128, 0, stream>>>(
      h1, ef, ei, wts+OW_E2A, wts+OB_E2A, wts+OW_E2B, wts+OB_E2B, msg2);
  gather2_kernel<<<(NN*4 + 255)/256, 256, 0, stream>>>(h1, msg2, rowptr, csr, wts+OW_R2, wts+OB_R2, h2);

  head_kernel<<<NG, 64, 0, stream>>>(h2, x_att, batch,
      wts+OW_L1, wts+OB_L1, wts+OW_L2, wts+OB_L2, d_out, flagp);
}